// Round 6
// baseline (146.606 us; speedup 1.0000x reference)
//
#include <hip/hip_runtime.h>

typedef unsigned short u16;
typedef unsigned int u32;

typedef __bf16 bf16x8 __attribute__((ext_vector_type(8)));
typedef float f32x16 __attribute__((ext_vector_type(16)));

#define OUT_F 4096
#define IN_F 4096
#define M_ROWS 4096              // 2 * 2048
#define NUM_GROUPS ((OUT_F * IN_F) / 32)   // 524288

#define TILE_E (256 * 64)        // u16 elements per LDS tile buffer (32 KB)

// ---------- helpers ----------

__device__ __forceinline__ u16 f2bf(float f) {
    union { float f; u32 u; } c; c.f = f;
    u32 u = c.u;
    u += 0x7fffu + ((u >> 16) & 1u);   // round-to-nearest-even (finite inputs)
    return (u16)(u >> 16);
}

__device__ __forceinline__ u32 pk2(float a, float b) {
    return (u32)f2bf(a) | ((u32)f2bf(b) << 16);
}

// async global -> LDS, 16 bytes per lane (global_load_lds_dwordx4)
__device__ __forceinline__ void async_copy16(const u16* g, u16* l) {
    __builtin_amdgcn_global_load_lds(
        (const __attribute__((address_space(1))) u32*)g,
        (__attribute__((address_space(3))) u32*)l,
        16, 0, 0);
}

// 32-bit LDS byte address for inline-asm ds_read
__device__ __forceinline__ u32 lds_addr(const u16* p) {
    return (u32)(uintptr_t)(const __attribute__((address_space(3))) u16*)p;
}

// ---------- fused prep (unchanged — not the bottleneck) ----------
__global__ __launch_bounds__(256) void prep_kernel(
        const float* __restrict__ x, const int* __restrict__ q,
        const float* __restrict__ scales,
        u16* __restrict__ W, u16* __restrict__ Xb) {
    int bid = blockIdx.x;
    int tid = threadIdx.x;
    if (bid < 8192) {
        int t = bid * 256 + tid;                 // [0, NUM_TRIPLETS)
        int b0 = q[3 * t];
        int b1 = q[3 * t + 1];
        int b2 = q[3 * t + 2];
        float mv = scales[t >> 2];
        float s = mv * (2.0f / 7.0f);            // w = v*s - mv
        float o = -mv;

        int v0 = b0 & 7;
        int v1 = (b0 >> 3) & 7;
        int v2 = ((b0 >> 6) & 3) | ((b1 & 1) << 2);
        int v3 = (b1 >> 1) & 7;
        int v4 = (b1 >> 4) & 7;
        int v5 = ((b1 >> 7) & 1) | ((b2 & 3) << 1);
        int v6 = (b2 >> 2) & 7;
        int v7 = (b2 >> 5) & 7;
        uint4 w;
        w.x = pk2(fmaf((float)v0, s, o), fmaf((float)v1, s, o));
        w.y = pk2(fmaf((float)v2, s, o), fmaf((float)v3, s, o));
        w.z = pk2(fmaf((float)v4, s, o), fmaf((float)v5, s, o));
        w.w = pk2(fmaf((float)v6, s, o), fmaf((float)v7, s, o));
        ((uint4*)W)[t] = w;
    } else {
        int i = (bid - 8192) * 256 + tid;
        const float4* p = (const float4*)x + (size_t)i * 2;
        float4 u = p[0], v = p[1];
        uint4 w;
        w.x = pk2(u.x, u.y);
        w.y = pk2(u.z, u.w);
        w.z = pk2(v.x, v.y);
        w.w = pk2(v.z, v.w);
        ((uint4*)Xb)[i] = w;
    }
}

// ---------- 256x256 bf16 GEMM, 32x32x16 MFMA, single barrier/tile ----------
// C[m][n] = sum_k A[m][k]*B[n][k] + bias[n]
//
// R5 post-mortem: R2(8bar)=R4(4bar)=R5(1bar) within 10% -> scheduling is NOT
// the lever; per-tile pinned at ~4370cyc = 16x16 MFMA issue floor (2480cyc
// @2075TF rate) + ~1900 unhidden LDS. R6: switch to 32x32x16 MFMA
// (measured rate 2495TF): HALF the MFMA instructions, floor 2066cyc/tile,
// same LDS traffic (24 b128/wave/tile), 8 independent acc per k-phase.
//  - operand layout: A/B row|col = lane&31, k = (lane>>5)*8+e
//  - C/D (m74/m101): col=lane&31, row=(reg&3)+8*(reg>>2)+4*(lane>>5)
//  - chunk-XOR swizzle kept; bank audit: each 8-row group covers all four
//    32B blocks -> 8 rounds/1024B = conflict-free.
//  - counted-lgkm ladder: issue k0,k1(12 reads); W(6)->MFMA k0; issue k2,
//    W(6)->k1; issue k3, W(6)->k2; W(0)->k3. E/O register sets, WAR safe
//    (in-order issue; HW scoreboards DS-return vs in-flight MFMA reads).
//  - staging/prologue/XCD swizzle/1-barrier-tile frozen from R5.
__global__ __launch_bounds__(512, 2) void gemm_bt_kernel(
        const u16* __restrict__ A, const u16* __restrict__ B,
        const float* __restrict__ bias, float* __restrict__ C) {
    __shared__ u16 sA[2 * TILE_E];
    __shared__ u16 sB[2 * TILE_E];

    const int tid = threadIdx.x;
    const int lane = tid & 63;
    const int w = tid >> 6;          // wave 0..7
    const int wr = w >> 2;           // wave row 0..1  (rows wr*128 + [0,128))
    const int wc = w & 3;            // wave col 0..3  (cols wc*64 + [0,64))
    const int l31 = lane & 31;
    const int hi = lane >> 5;
    const int l7 = lane & 7;
    const int l72 = (l7 >> 1) & 3;
    const int lb0 = l7 & 1;

    // XCD-aware bijective swizzle: 256 blocks, 8 XCDs, 32 contiguous tiles/XCD
    const int lin = blockIdx.x;
    const int wg = (lin & 7) * 32 + (lin >> 3);
    const int mb = (wg >> 4) * 256;   // M tile
    const int nb = (wg & 15) * 256;   // N tile

    // staging geometry: half-tile = 128 rows x 64 bf16 = 2 x 512thr x 16B
    int offg[2], offl[2];
#pragma unroll
    for (int p = 0; p < 2; ++p) {
        int s = p * 512 + tid;
        int rl = s >> 3, pc = s & 7;
        int lc = pc ^ (rl & 7);          // XOR swizzle on global source
        offg[p] = rl * IN_F + lc * 8;
        offl[p] = rl * 64 + pc * 8;      // lane-contiguous LDS dest
    }
    const u16* baseA = A + (size_t)mb * IN_F;
    const u16* baseB = B + (size_t)nb * IN_F;

    auto STAGE = [&](u16* lbase, const u16* gbase, int ko, int h) {
#pragma unroll
        for (int p = 0; p < 2; ++p)
            async_copy16(gbase + h * (128 * IN_F) + offg[p] + ko,
                         lbase + h * (128 * 64) + offl[p]);
    };

    // ds_read bases (bytes), one per k-step ks (k = ks*16 + hi*8):
    //   logical chunk = ks*2 + hi; physical = logical ^ (row&7)
    //   = 16*(hi^lb0) + 32*(ks^l72)  [bit decomposition]
    // row term: (wr*128 + l31)*128 (A) / (wc*64 + l31)*128 (B).
    // rb adds rb*32 rows = offset:rb*4096; cb adds cb*32 rows = cb*4096.
    const u32 sAb = lds_addr(sA);
    const u32 sBb = lds_addr(sB);
    const u32 aS = sAb + (u32)((wr * 128 + l31) * 128 + 16 * (hi ^ lb0));
    const u32 bS = sBb + (u32)((wc * 64 + l31) * 128 + 16 * (hi ^ lb0));
    u32 aK[4], bK[4];
#pragma unroll
    for (int ks = 0; ks < 4; ++ks) {
        aK[ks] = aS + (u32)(32 * (ks ^ l72));
        bK[ks] = bS + (u32)(32 * (ks ^ l72));
    }

    // bias for this thread's 2 output columns (cb = 0,1)
    float bj[2];
#pragma unroll
    for (int cb = 0; cb < 2; ++cb)
        bj[cb] = bias[nb + wc * 64 + cb * 32 + l31];

    f32x16 acc[4][2];
#pragma unroll
    for (int rb = 0; rb < 4; ++rb)
#pragma unroll
        for (int cb = 0; cb < 2; ++cb) acc[rb][cb] = (f32x16)0.0f;

    bf16x8 avE[4], bvE[2];    // even k-steps (k0, k2)
    bf16x8 avO[4], bvO[2];    // odd  k-steps (k1, k3)

#define DSR(dst, base, IMM) \
    asm volatile("ds_read_b128 %0, %1 offset:" #IMM \
                 : "=v"(dst) : "v"(base))

#define WAITG(N) \
    asm volatile("s_waitcnt lgkmcnt(" #N ")"); \
    __builtin_amdgcn_sched_barrier(0);

// one k-step: 8 independent 32x32x16 MFMAs (4 row-blocks x 2 col-blocks)
#define MFMA_K(AV, BV) \
    acc[0][0] = __builtin_amdgcn_mfma_f32_32x32x16_bf16(AV[0], BV[0], acc[0][0], 0, 0, 0); \
    acc[1][0] = __builtin_amdgcn_mfma_f32_32x32x16_bf16(AV[1], BV[0], acc[1][0], 0, 0, 0); \
    acc[2][0] = __builtin_amdgcn_mfma_f32_32x32x16_bf16(AV[2], BV[0], acc[2][0], 0, 0, 0); \
    acc[3][0] = __builtin_amdgcn_mfma_f32_32x32x16_bf16(AV[3], BV[0], acc[3][0], 0, 0, 0); \
    acc[0][1] = __builtin_amdgcn_mfma_f32_32x32x16_bf16(AV[0], BV[1], acc[0][1], 0, 0, 0); \
    acc[1][1] = __builtin_amdgcn_mfma_f32_32x32x16_bf16(AV[1], BV[1], acc[1][1], 0, 0, 0); \
    acc[2][1] = __builtin_amdgcn_mfma_f32_32x32x16_bf16(AV[2], BV[1], acc[2][1], 0, 0, 0); \
    acc[3][1] = __builtin_amdgcn_mfma_f32_32x32x16_bf16(AV[3], BV[1], acc[3][1], 0, 0, 0);

#define READ_K(AV, BV, AT, BT) \
    DSR(AV[0], AT, 0);  DSR(AV[1], AT, 4096); \
    DSR(AV[2], AT, 8192); DSR(AV[3], AT, 12288); \
    DSR(BV[0], BT, 0);  DSR(BV[1], BT, 4096);

    // ---- prologue: stage tile 0 into buf0, drain, publish ----
    STAGE(sA, baseA, 0, 0);
    STAGE(sA, baseA, 0, 1);
    STAGE(sB, baseB, 0, 0);
    STAGE(sB, baseB, 0, 1);
    asm volatile("s_waitcnt vmcnt(0)");
    __builtin_amdgcn_s_barrier();

#pragma unroll 1
    for (int t = 0; t < 64; ++t) {
        const int cur = t & 1;
        const u32 curOff = (u32)cur << 15;       // cur * 32768 B = TILE_E*2
        const u32 aT0 = aK[0] + curOff, aT1 = aK[1] + curOff;
        const u32 aT2 = aK[2] + curOff, aT3 = aK[3] + curOff;
        const u32 bT0 = bK[0] + curOff, bT1 = bK[1] + curOff;
        const u32 bT2 = bK[2] + curOff, bT3 = bK[3] + curOff;
        u16* aNx = sA + (cur ^ 1) * TILE_E;
        u16* bNx = sB + (cur ^ 1) * TILE_E;
        const int ko1 = ((t + 1) & 63) << 6;

        // ---- issue k0 (->E) and k1 (->O): 12 reads ----
        READ_K(avE, bvE, aT0, bT0);
        READ_K(avO, bvO, aT1, bT1);

        // ---- issue all stages for tile t+1 into buf^1 ----
        STAGE(aNx, baseA, ko1, 0);
        STAGE(aNx, baseA, ko1, 1);
        STAGE(bNx, baseB, ko1, 0);
        STAGE(bNx, baseB, ko1, 1);
        __builtin_amdgcn_sched_barrier(0);

        // ---- k0 ----
        __builtin_amdgcn_s_setprio(1);
        WAITG(6); MFMA_K(avE, bvE);
        __builtin_amdgcn_sched_barrier(0);
        __builtin_amdgcn_s_setprio(0);

        // ---- issue k2 (->E, registers retired by k0's MFMAs) ----
        READ_K(avE, bvE, aT2, bT2);

        // ---- k1 ----
        __builtin_amdgcn_s_setprio(1);
        WAITG(6); MFMA_K(avO, bvO);
        __builtin_amdgcn_sched_barrier(0);
        __builtin_amdgcn_s_setprio(0);

        // ---- issue k3 (->O) ----
        READ_K(avO, bvO, aT3, bT3);

        // ---- k2, k3 ----
        __builtin_amdgcn_s_setprio(1);
        WAITG(6); MFMA_K(avE, bvE);
        WAITG(0); MFMA_K(avO, bvO);
        __builtin_amdgcn_sched_barrier(0);
        __builtin_amdgcn_s_setprio(0);

        // ---- tile boundary: own stages complete, publish to block ----
        asm volatile("s_waitcnt vmcnt(0)");
        __builtin_amdgcn_s_barrier();
    }

#undef DSR
#undef WAITG
#undef MFMA_K
#undef READ_K

    // drain trailing (wrapped t=64) prefetches before epilogue
    asm volatile("s_waitcnt vmcnt(0)");

    // ---- epilogue: C[row][col] = acc + bias[col]
    // 32x32 C/D: col = lane&31, row = (reg&3) + 8*(reg>>2) + 4*hi
#pragma unroll
    for (int rb = 0; rb < 4; ++rb) {
        const int m0 = mb + wr * 128 + rb * 32 + 4 * hi;
#pragma unroll
        for (int cb = 0; cb < 2; ++cb) {
            const int col = nb + wc * 64 + cb * 32 + l31;
            const float bc = bj[cb];
#pragma unroll
            for (int r = 0; r < 16; ++r) {
                const int row = m0 + (r & 3) + 8 * (r >> 2);
                C[(size_t)row * OUT_F + col] = acc[rb][cb][r] + bc;
            }
        }
    }
}

extern "C" void kernel_launch(void* const* d_in, const int* in_sizes, int n_in,
                              void* d_out, int out_size, void* d_ws, size_t ws_size,
                              hipStream_t stream) {
    const float* x = (const float*)d_in[0];       // [2,2048,4096] fp32
    const int* wq = (const int*)d_in[1];          // [NUM_GROUPS*12]
    const float* wn = (const float*)d_in[2];      // [NUM_GROUPS]
    const float* bias = (const float*)d_in[3];    // [4096]
    float* out = (float*)d_out;                   // [2,2048,4096] fp32

    u16* Wb = (u16*)d_ws;                         // 32 MB
    u16* Xb = Wb + (size_t)OUT_F * IN_F;          // 32 MB

    prep_kernel<<<16384, 256, 0, stream>>>(x, wq, wn, Wb, Xb);
    gemm_bt_kernel<<<dim3(256), 512, 0, stream>>>(Xb, Wb, bias, out);
}

// Round 7
// 143.018 us; speedup vs baseline: 1.0251x; 1.0251x over previous
//
#include <hip/hip_runtime.h>

typedef unsigned short u16;
typedef unsigned int u32;

typedef __bf16 bf16x8 __attribute__((ext_vector_type(8)));
typedef float f32x4 __attribute__((ext_vector_type(4)));

#define OUT_F 4096
#define IN_F 4096
#define M_ROWS 4096              // 2 * 2048
#define NUM_GROUPS ((OUT_F * IN_F) / 32)   // 524288

#define TILE_E (256 * 64)        // u16 elements per LDS tile buffer (32 KB)

// ---------- helpers ----------

__device__ __forceinline__ u16 f2bf(float f) {
    union { float f; u32 u; } c; c.f = f;
    u32 u = c.u;
    u += 0x7fffu + ((u >> 16) & 1u);   // round-to-nearest-even (finite inputs)
    return (u16)(u >> 16);
}

__device__ __forceinline__ u32 pk2(float a, float b) {
    return (u32)f2bf(a) | ((u32)f2bf(b) << 16);
}

// async global -> LDS, 16 bytes per lane (global_load_lds_dwordx4)
__device__ __forceinline__ void async_copy16(const u16* g, u16* l) {
    __builtin_amdgcn_global_load_lds(
        (const __attribute__((address_space(1))) u32*)g,
        (__attribute__((address_space(3))) u32*)l,
        16, 0, 0);
}

// 32-bit LDS byte address for inline-asm ds_read
__device__ __forceinline__ u32 lds_addr(const u16* p) {
    return (u32)(uintptr_t)(const __attribute__((address_space(3))) u16*)p;
}

// ---------- fused prep (unchanged — ~25 us HBM floor, later target) ----------
__global__ __launch_bounds__(256) void prep_kernel(
        const float* __restrict__ x, const int* __restrict__ q,
        const float* __restrict__ scales,
        u16* __restrict__ W, u16* __restrict__ Xb) {
    int bid = blockIdx.x;
    int tid = threadIdx.x;
    if (bid < 8192) {
        int t = bid * 256 + tid;                 // [0, NUM_TRIPLETS)
        int b0 = q[3 * t];
        int b1 = q[3 * t + 1];
        int b2 = q[3 * t + 2];
        float mv = scales[t >> 2];
        float s = mv * (2.0f / 7.0f);            // w = v*s - mv
        float o = -mv;

        int v0 = b0 & 7;
        int v1 = (b0 >> 3) & 7;
        int v2 = ((b0 >> 6) & 3) | ((b1 & 1) << 2);
        int v3 = (b1 >> 1) & 7;
        int v4 = (b1 >> 4) & 7;
        int v5 = ((b1 >> 7) & 1) | ((b2 & 3) << 1);
        int v6 = (b2 >> 2) & 7;
        int v7 = (b2 >> 5) & 7;
        uint4 w;
        w.x = pk2(fmaf((float)v0, s, o), fmaf((float)v1, s, o));
        w.y = pk2(fmaf((float)v2, s, o), fmaf((float)v3, s, o));
        w.z = pk2(fmaf((float)v4, s, o), fmaf((float)v5, s, o));
        w.w = pk2(fmaf((float)v6, s, o), fmaf((float)v7, s, o));
        ((uint4*)W)[t] = w;
    } else {
        int i = (bid - 8192) * 256 + tid;
        const float4* p = (const float4*)x + (size_t)i * 2;
        float4 u = p[0], v = p[1];
        uint4 w;
        w.x = pk2(u.x, u.y);
        w.y = pk2(u.z, u.w);
        w.z = pk2(v.x, v.y);
        w.w = pk2(v.z, v.w);
        ((uint4*)Xb)[i] = w;
    }
}

// ---------- 256x256 bf16 GEMM with cross-barrier pre-read pipeline ----------
// C[m][n] = sum_k A[m][k]*B[n][k] + bias[n]
//
// R6 post-mortem: 32x32 shape regressed (12.6M bank conflicts — audit wrong);
// reverted. R2/R4/R5 all land at ~sum(MFMA 2484 + port 1900) cyc/tile: with
// barrier-locked waves, ds_reads only issue post-barrier, so the CU alternates
// port-burst / MFMA-burst with no overlap. R7: PRE-READ the next tile's first
// quadrant operands (bv0+A0, 12 ds_reads) BEFORE the tile-end barrier, so Q0
// starts immediately post-barrier and the port drains under MFMA.
//   per tile: [entry: 12 pre-reads outstanding]
//     stage S(t+1)->buf^1 (8 gloads)
//     Q0 (a0v x bv0C): ladder 6/4/2/0          (pre-reads: likely complete)
//     issue b1v(4)+a1v(8) from buf cur
//     Q1 (a0v x b1v): WAITG(8);  Q2 (a1v x b1v): ladder 6/4/2/0
//     vmcnt(0); s_barrier        <- MID: publishes S(t+1) to all waves
//     pre-read next k0: bv0N(4)+a0v(8) from buf^1   [cross end-barrier]
//     Q3 (a1v x bv0C): no waits
//     s_barrier                  <- END: WAR guard for S(t+2)->buf cur
// Hazards audited: all buf-cur reads lgkm-complete before END (Q2 ladder
// ends W0); pre-reads target buf^1, disjoint from S(t+2)->buf cur; register
// WARs safe by in-order issue (MFMA reads operands at issue). bv0 ping-pongs
// by tile parity (manual 2x unroll); a0v reused for pre-read (dead post-Q1).
__global__ __launch_bounds__(512, 2) void gemm_bt_kernel(
        const u16* __restrict__ A, const u16* __restrict__ B,
        const float* __restrict__ bias, float* __restrict__ C) {
    __shared__ u16 sA[2 * TILE_E];
    __shared__ u16 sB[2 * TILE_E];

    const int tid = threadIdx.x;
    const int lane = tid & 63;
    const int w = tid >> 6;          // wave 0..7
    const int wr = w >> 2;           // wave row 0..1
    const int wc = w & 3;            // wave col 0..3
    const int ln = lane & 15;
    const int quad = lane >> 4;
    const int lnx = ln & 7;

    // XCD-aware bijective swizzle: 256 blocks, 8 XCDs, 32 contiguous tiles/XCD
    const int lin = blockIdx.x;
    const int wg = (lin & 7) * 32 + (lin >> 3);
    const int mb = (wg >> 4) * 256;   // M tile
    const int nb = (wg & 15) * 256;   // N tile

    // staging geometry: half-tile = 128 rows x 64 bf16 = 2 x 512thr x 16B
    int offg[2], offl[2];
#pragma unroll
    for (int p = 0; p < 2; ++p) {
        int s = p * 512 + tid;
        int rl = s >> 3, pc = s & 7;
        int lc = pc ^ (rl & 7);          // XOR swizzle on global source
        offg[p] = rl * IN_F + lc * 8;
        offl[p] = rl * 64 + pc * 8;      // lane-contiguous LDS dest
    }
    const u16* baseA = A + (size_t)mb * IN_F;
    const u16* baseB = B + (size_t)nb * IN_F;

    auto STAGE = [&](u16* lbase, const u16* gbase, int ko, int h) {
#pragma unroll
        for (int p = 0; p < 2; ++p)
            async_copy16(gbase + h * (128 * IN_F) + offg[p] + ko,
                         lbase + h * (128 * 64) + offl[p]);
    };

    // ds_read bases (bytes), kk in {0,1} selects base; buffer via X/Y sets:
    //   A: [buf] + wr*8192 + ln*128 + ((kk*4+quad)^lnx)*16  (+ imm mh*16384+i*2048)
    //   B: [buf] + wc*4096 + ln*128 + ((kk*4+quad)^lnx)*16  (+ imm nh*16384+j*2048)
    const u32 sAb = lds_addr(sA);
    const u32 sBb = lds_addr(sB);
    const u32 aX0 = sAb + (u32)(wr * 8192 + ln * 128 + ((quad ^ lnx) * 16));
    const u32 aX1 = sAb + (u32)(wr * 8192 + ln * 128 + (((4 + quad) ^ lnx) * 16));
    const u32 bX0 = sBb + (u32)(wc * 4096 + ln * 128 + ((quad ^ lnx) * 16));
    const u32 bX1 = sBb + (u32)(wc * 4096 + ln * 128 + (((4 + quad) ^ lnx) * 16));
    const u32 aY0 = aX0 + 32768, aY1 = aX1 + 32768;
    const u32 bY0 = bX0 + 32768, bY1 = bX1 + 32768;

    u16* const sA0 = sA;            u16* const sA1 = sA + TILE_E;
    u16* const sB0 = sB;            u16* const sB1 = sB + TILE_E;

    // bias for this thread's 4 output column groups
    float bj[2][2];
#pragma unroll
    for (int nh = 0; nh < 2; ++nh)
#pragma unroll
        for (int j = 0; j < 2; ++j)
            bj[nh][j] = bias[nb + nh * 128 + wc * 32 + j * 16 + ln];

    f32x4 acc[8][4];
#pragma unroll
    for (int i = 0; i < 8; ++i)
#pragma unroll
        for (int j = 0; j < 4; ++j) acc[i][j] = (f32x4)0.0f;

    bf16x8 a0v[4][2];     // A0 fragments (pre-read), reused each tile
    bf16x8 a1v[4][2];     // A1 fragments (mid-read)
    bf16x8 b1v[2][2];     // B1 fragments (mid-read)
    bf16x8 b0x[2][2];     // bv0 ping (even tiles' B0)
    bf16x8 b0y[2][2];     // bv0 pong (odd tiles' B0)

#define DSR(dst, base, IMM) \
    asm volatile("ds_read_b128 %0, %1 offset:" #IMM \
                 : "=v"(dst) : "v"(base))

#define WAITG(N) \
    asm volatile("s_waitcnt lgkmcnt(" #N ")"); \
    __builtin_amdgcn_sched_barrier(0);

// 4 MFMAs: AV[AI] x BV -> acc[ACR][J0], acc[ACR][J1]
#define MG(AV, AI, ACR, J0, J1, BV) \
    acc[ACR][J0] = __builtin_amdgcn_mfma_f32_16x16x32_bf16( \
        AV[AI][0], BV[0][0], acc[ACR][J0], 0, 0, 0); \
    acc[ACR][J0] = __builtin_amdgcn_mfma_f32_16x16x32_bf16( \
        AV[AI][1], BV[0][1], acc[ACR][J0], 0, 0, 0); \
    acc[ACR][J1] = __builtin_amdgcn_mfma_f32_16x16x32_bf16( \
        AV[AI][0], BV[1][0], acc[ACR][J1], 0, 0, 0); \
    acc[ACR][J1] = __builtin_amdgcn_mfma_f32_16x16x32_bf16( \
        AV[AI][1], BV[1][1], acc[ACR][J1], 0, 0, 0);

// one K-tile. AB0/AB1/BB0/BB1: current-buffer bases; N*: next-buffer bases;
// AWR/BWR: stage target (next buffer); KO1: stage k-offset; B0C/B0N: bv0 sets.
#define TILE_ITER(AB0, AB1, BB0, BB1, NA0, NA1, NB0, NB1, AWR, BWR, KO1, B0C, B0N) \
    STAGE(AWR, baseA, KO1, 0); \
    STAGE(AWR, baseA, KO1, 1); \
    STAGE(BWR, baseB, KO1, 0); \
    STAGE(BWR, baseB, KO1, 1); \
    __builtin_amdgcn_sched_barrier(0); \
    /* Q0: a0v x B0C (12 pre-reads in queue) */ \
    __builtin_amdgcn_s_setprio(1); \
    WAITG(6); MG(a0v, 0, 0, 0, 1, B0C); \
    WAITG(4); MG(a0v, 1, 1, 0, 1, B0C); \
    WAITG(2); MG(a0v, 2, 2, 0, 1, B0C); \
    WAITG(0); MG(a0v, 3, 3, 0, 1, B0C); \
    __builtin_amdgcn_sched_barrier(0); \
    __builtin_amdgcn_s_setprio(0); \
    /* mid reads: b1v(4), a1v(8) from current buffer */ \
    DSR(b1v[0][0], BB0, 16384);  DSR(b1v[0][1], BB1, 16384); \
    DSR(b1v[1][0], BB0, 18432);  DSR(b1v[1][1], BB1, 18432); \
    DSR(a1v[0][0], AB0, 16384);  DSR(a1v[0][1], AB1, 16384); \
    DSR(a1v[1][0], AB0, 18432);  DSR(a1v[1][1], AB1, 18432); \
    DSR(a1v[2][0], AB0, 20480);  DSR(a1v[2][1], AB1, 20480); \
    DSR(a1v[3][0], AB0, 22528);  DSR(a1v[3][1], AB1, 22528); \
    __builtin_amdgcn_sched_barrier(0); \
    /* Q1: a0v x b1v ; Q2: a1v x b1v */ \
    __builtin_amdgcn_s_setprio(1); \
    WAITG(8); MG(a0v, 0, 0, 2, 3, b1v); \
    MG(a0v, 1, 1, 2, 3, b1v); \
    MG(a0v, 2, 2, 2, 3, b1v); \
    MG(a0v, 3, 3, 2, 3, b1v); \
    WAITG(6); MG(a1v, 0, 4, 2, 3, b1v); \
    WAITG(4); MG(a1v, 1, 5, 2, 3, b1v); \
    WAITG(2); MG(a1v, 2, 6, 2, 3, b1v); \
    WAITG(0); MG(a1v, 3, 7, 2, 3, b1v); \
    __builtin_amdgcn_sched_barrier(0); \
    __builtin_amdgcn_s_setprio(0); \
    /* MID barrier: publish S(t+1) */ \
    asm volatile("s_waitcnt vmcnt(0)"); \
    __builtin_amdgcn_s_barrier(); \
    /* pre-reads for next tile (buf^1): B0N(4), a0v(8) */ \
    DSR(B0N[0][0], NB0, 0);     DSR(B0N[0][1], NB1, 0); \
    DSR(B0N[1][0], NB0, 2048);  DSR(B0N[1][1], NB1, 2048); \
    DSR(a0v[0][0], NA0, 0);     DSR(a0v[0][1], NA1, 0); \
    DSR(a0v[1][0], NA0, 2048);  DSR(a0v[1][1], NA1, 2048); \
    DSR(a0v[2][0], NA0, 4096);  DSR(a0v[2][1], NA1, 4096); \
    DSR(a0v[3][0], NA0, 6144);  DSR(a0v[3][1], NA1, 6144); \
    __builtin_amdgcn_sched_barrier(0); \
    /* Q3: a1v x B0C, no waits; pre-reads drain underneath */ \
    __builtin_amdgcn_s_setprio(1); \
    MG(a1v, 0, 4, 0, 1, B0C); \
    MG(a1v, 1, 5, 0, 1, B0C); \
    MG(a1v, 2, 6, 0, 1, B0C); \
    MG(a1v, 3, 7, 0, 1, B0C); \
    __builtin_amdgcn_sched_barrier(0); \
    __builtin_amdgcn_s_setprio(0); \
    /* END barrier: WAR guard (12 pre-reads stay outstanding) */ \
    __builtin_amdgcn_s_barrier();

    // ---- prologue: stage tile0 -> buf0, publish, pre-read its k0 ----
    STAGE(sA0, baseA, 0, 0);
    STAGE(sA0, baseA, 0, 1);
    STAGE(sB0, baseB, 0, 0);
    STAGE(sB0, baseB, 0, 1);
    asm volatile("s_waitcnt vmcnt(0)");
    __builtin_amdgcn_s_barrier();
    DSR(b0x[0][0], bX0, 0);     DSR(b0x[0][1], bX1, 0);
    DSR(b0x[1][0], bX0, 2048);  DSR(b0x[1][1], bX1, 2048);
    DSR(a0v[0][0], aX0, 0);     DSR(a0v[0][1], aX1, 0);
    DSR(a0v[1][0], aX0, 2048);  DSR(a0v[1][1], aX1, 2048);
    DSR(a0v[2][0], aX0, 4096);  DSR(a0v[2][1], aX1, 4096);
    DSR(a0v[3][0], aX0, 6144);  DSR(a0v[3][1], aX1, 6144);
    __builtin_amdgcn_sched_barrier(0);

#pragma unroll 1
    for (int tp = 0; tp < 32; ++tp) {
        const int ko1e = ((2 * tp + 1) & 63) << 6;
        const int ko1o = ((2 * tp + 2) & 63) << 6;
        // even tile: cur = buf0 (X), next = buf1 (Y), bv0C = b0x
        TILE_ITER(aX0, aX1, bX0, bX1, aY0, aY1, bY0, bY1,
                  sA1, sB1, ko1e, b0x, b0y);
        // odd tile: cur = buf1 (Y), next = buf0 (X), bv0C = b0y
        TILE_ITER(aY0, aY1, bY0, bY1, aX0, aX1, bX0, bX1,
                  sA0, sB0, ko1o, b0y, b0x);
    }

#undef DSR
#undef WAITG
#undef MG
#undef TILE_ITER

    // drain trailing pre-reads + wrapped stages before epilogue (register
    // reuse by the epilogue would race in-flight DS returns otherwise)
    asm volatile("s_waitcnt lgkmcnt(0)");
    asm volatile("s_waitcnt vmcnt(0)");
    __builtin_amdgcn_sched_barrier(0);

    // ---- epilogue: C[row][col] = acc + bias[col]
#pragma unroll
    for (int ai = 0; ai < 8; ++ai) {
        const int mh = ai >> 2, i = ai & 3;
        const int mrow = mb + mh * 128 + wr * 64 + i * 16 + quad * 4;
#pragma unroll
        for (int j4 = 0; j4 < 4; ++j4) {
            const int nh = j4 >> 1, j = j4 & 1;
            const int col = nb + nh * 128 + wc * 32 + j * 16 + ln;
            float* cp = C + (size_t)mrow * OUT_F + col;
#pragma unroll
            for (int r = 0; r < 4; ++r)
                cp[(size_t)r * OUT_F] = acc[ai][j4][r] + bj[nh][j];
        }
    }
}

extern "C" void kernel_launch(void* const* d_in, const int* in_sizes, int n_in,
                              void* d_out, int out_size, void* d_ws, size_t ws_size,
                              hipStream_t stream) {
    const float* x = (const float*)d_in[0];       // [2,2048,4096] fp32
    const int* wq = (const int*)d_in[1];          // [NUM_GROUPS*12]
    const float* wn = (const float*)d_in[2];      // [NUM_GROUPS]
    const float* bias = (const float*)d_in[3];    // [4096]
    float* out = (float*)d_out;                   // [2,2048,4096] fp32

    u16* Wb = (u16*)d_ws;                         // 32 MB
    u16* Xb = Wb + (size_t)OUT_F * IN_F;          // 32 MB

    prep_kernel<<<16384, 256, 0, stream>>>(x, wq, wn, Wb, Xb);
    gemm_bt_kernel<<<dim3(256), 512, 0, stream>>>(Xb, Wb, bias, out);
}

// Round 8
// 141.023 us; speedup vs baseline: 1.0396x; 1.0141x over previous
//
#include <hip/hip_runtime.h>

typedef unsigned short u16;
typedef unsigned int u32;

typedef __bf16 bf16x8 __attribute__((ext_vector_type(8)));
typedef float f32x4 __attribute__((ext_vector_type(4)));

#define OUT_F 4096
#define IN_F 4096
#define M_ROWS 4096              // 2 * 2048
#define NUM_GROUPS ((OUT_F * IN_F) / 32)   // 524288

// ---------- helpers ----------

__device__ __forceinline__ u16 f2bf(float f) {
    union { float f; u32 u; } c; c.f = f;
    u32 u = c.u;
    u += 0x7fffu + ((u >> 16) & 1u);   // round-to-nearest-even (finite inputs)
    return (u16)(u >> 16);
}

__device__ __forceinline__ u32 pk2(float a, float b) {
    return (u32)f2bf(a) | ((u32)f2bf(b) << 16);
}

// async global -> LDS, 16 bytes per lane (global_load_lds_dwordx4)
__device__ __forceinline__ void async_copy16(const u16* g, u16* l) {
    __builtin_amdgcn_global_load_lds(
        (const __attribute__((address_space(1))) u32*)g,
        (__attribute__((address_space(3))) u32*)l,
        16, 0, 0);
}

// 32-bit LDS byte address for inline-asm ds_read
__device__ __forceinline__ u32 lds_addr(const u16* p) {
    return (u32)(uintptr_t)(const __attribute__((address_space(3))) u16*)p;
}

// ---------- fused prep (unchanged — not the bottleneck) ----------
__global__ __launch_bounds__(256) void prep_kernel(
        const float* __restrict__ x, const int* __restrict__ q,
        const float* __restrict__ scales,
        u16* __restrict__ W, u16* __restrict__ Xb) {
    int bid = blockIdx.x;
    int tid = threadIdx.x;
    if (bid < 8192) {
        int t = bid * 256 + tid;                 // [0, NUM_TRIPLETS)
        int b0 = q[3 * t];
        int b1 = q[3 * t + 1];
        int b2 = q[3 * t + 2];
        float mv = scales[t >> 2];
        float s = mv * (2.0f / 7.0f);            // w = v*s - mv
        float o = -mv;

        int v0 = b0 & 7;
        int v1 = (b0 >> 3) & 7;
        int v2 = ((b0 >> 6) & 3) | ((b1 & 1) << 2);
        int v3 = (b1 >> 1) & 7;
        int v4 = (b1 >> 4) & 7;
        int v5 = ((b1 >> 7) & 1) | ((b2 & 3) << 1);
        int v6 = (b2 >> 2) & 7;
        int v7 = (b2 >> 5) & 7;
        uint4 w;
        w.x = pk2(fmaf((float)v0, s, o), fmaf((float)v1, s, o));
        w.y = pk2(fmaf((float)v2, s, o), fmaf((float)v3, s, o));
        w.z = pk2(fmaf((float)v4, s, o), fmaf((float)v5, s, o));
        w.w = pk2(fmaf((float)v6, s, o), fmaf((float)v7, s, o));
        ((uint4*)W)[t] = w;
    } else {
        int i = (bid - 8192) * 256 + tid;
        const float4* p = (const float4*)x + (size_t)i * 2;
        float4 u = p[0], v = p[1];
        uint4 w;
        w.x = pk2(u.x, u.y);
        w.y = pk2(u.z, u.w);
        w.z = pk2(v.x, v.y);
        w.w = pk2(v.z, v.w);
        ((uint4*)Xb)[i] = w;
    }
}

// ---------- 256x128 tile, 2 blocks/CU, single-buffer bf16 GEMM ----------
// C[m][n] = sum_k A[m][k]*B[n][k] + bias[n]
//
// R2..R7 post-mortem: five different intra-block schedules all pinned at
// ~4400 cyc/tile = MFMA (2150) + LDS-port (2300) in SERIES. With 1 block/CU
// and barrier-coupled waves, port/MFMA overlap never materializes. R8 uses
// the mechanism PROVEN on this chip (m114/m97): independent co-resident
// blocks. Tile 256x128, 256 threads (4 waves 2Mx2N, per-wave 128x64 = same
// fragment geometry as R5), single-buffer LDS 48 KB -> 2 blocks/CU
// (grid 512 = 2/CU exact). Block schedule is trivially safe:
//   [24 ds_reads counted-ladder + 64 MFMA] bar [stage t+1] vmcnt(0) bar
// The exposed stage stall of one block is covered by the other block's
// compute; no cross-region hazards exist (reads all before barrier-1,
// writes all after; single buffer).
__global__ __launch_bounds__(256, 2) void gemm_bt_kernel(
        const u16* __restrict__ A, const u16* __restrict__ B,
        const float* __restrict__ bias, float* __restrict__ C) {
    __shared__ u16 sA[256 * 64];    // 32 KB
    __shared__ u16 sB[128 * 64];    // 16 KB

    const int tid = threadIdx.x;
    const int lane = tid & 63;
    const int w = tid >> 6;          // wave 0..3
    const int wr = w >> 1;           // wave row 0..1 (rows wr*128 + [0,128))
    const int wc = w & 1;            // wave col 0..1 (cols wc*64 + [0,64))
    const int ln = lane & 15;
    const int quad = lane >> 4;
    const int lnx = ln & 7;

    // XCD-aware bijective swizzle: 512 blocks, 8 XCDs, 64 contiguous/XCD.
    // wg = m*32 + n: consecutive wg share the A-panel (L2 locality).
    const int lin = blockIdx.x;
    const int wg = (lin & 7) * 64 + (lin >> 3);
    const int mb = (wg >> 5) * 256;   // M tile (16 tiles)
    const int nb = (wg & 31) * 128;   // N tile (32 tiles)

    // staging geometry: slot s = p*256+tid; row = s>>3, phys chunk = s&7,
    // logical chunk = pc ^ (row&7) (XOR swizzle on the global source).
    // A uses p=0..7 (rows 0..255), B uses p=0..3 (rows 0..127).
    int offg[8], offl[8];
#pragma unroll
    for (int p = 0; p < 8; ++p) {
        int s = p * 256 + tid;
        int rl = s >> 3, pc = s & 7;
        int lc = pc ^ (rl & 7);
        offg[p] = rl * IN_F + lc * 8;
        offl[p] = s * 8;                 // lane-contiguous LDS dest
    }
    const u16* baseA = A + (size_t)mb * IN_F;
    const u16* baseB = B + (size_t)nb * IN_F;

    // fragment read bases (bytes). Row stride 128 B.
    //   A-frag i (i<8): rows wr*128 + i*16 + ln  -> imm offset i*2048
    //   B-frag j (j<4): rows wc*64  + j*16 + ln  -> imm offset j*2048
    // kk in {0,1} picks chunk base ((kk*4+quad)^lnx)*16.
    const u32 sAb = lds_addr(sA);
    const u32 sBb = lds_addr(sB);
    const u32 aB0 = sAb + (u32)((wr * 128 + ln) * 128 + ((quad ^ lnx) * 16));
    const u32 aB1 = sAb + (u32)((wr * 128 + ln) * 128 + (((4 + quad) ^ lnx) * 16));
    const u32 bB0 = sBb + (u32)((wc * 64 + ln) * 128 + ((quad ^ lnx) * 16));
    const u32 bB1 = sBb + (u32)((wc * 64 + ln) * 128 + (((4 + quad) ^ lnx) * 16));

    // bias for this thread's 4 output column groups
    float bj[4];
#pragma unroll
    for (int j = 0; j < 4; ++j)
        bj[j] = bias[nb + wc * 64 + j * 16 + ln];

    f32x4 acc[8][4];
#pragma unroll
    for (int i = 0; i < 8; ++i)
#pragma unroll
        for (int j = 0; j < 4; ++j) acc[i][j] = (f32x4)0.0f;

    bf16x8 av[4][2];     // A fragments, 4 rows at a time (reused per batch)
    bf16x8 bv[4][2];     // B fragments, live whole tile

#define DSR(dst, base, IMM) \
    asm volatile("ds_read_b128 %0, %1 offset:" #IMM \
                 : "=v"(dst) : "v"(base))

#define WAITG(N) \
    asm volatile("s_waitcnt lgkmcnt(" #N ")"); \
    __builtin_amdgcn_sched_barrier(0);

// one A-row fragment x all 4 B-frags x 2 kk; same-acc ops are 4 apart
#define MROW(IR, ACR) \
    acc[ACR][0] = __builtin_amdgcn_mfma_f32_16x16x32_bf16( \
        av[IR][0], bv[0][0], acc[ACR][0], 0, 0, 0); \
    acc[ACR][1] = __builtin_amdgcn_mfma_f32_16x16x32_bf16( \
        av[IR][0], bv[1][0], acc[ACR][1], 0, 0, 0); \
    acc[ACR][2] = __builtin_amdgcn_mfma_f32_16x16x32_bf16( \
        av[IR][0], bv[2][0], acc[ACR][2], 0, 0, 0); \
    acc[ACR][3] = __builtin_amdgcn_mfma_f32_16x16x32_bf16( \
        av[IR][0], bv[3][0], acc[ACR][3], 0, 0, 0); \
    acc[ACR][0] = __builtin_amdgcn_mfma_f32_16x16x32_bf16( \
        av[IR][1], bv[0][1], acc[ACR][0], 0, 0, 0); \
    acc[ACR][1] = __builtin_amdgcn_mfma_f32_16x16x32_bf16( \
        av[IR][1], bv[1][1], acc[ACR][1], 0, 0, 0); \
    acc[ACR][2] = __builtin_amdgcn_mfma_f32_16x16x32_bf16( \
        av[IR][1], bv[2][1], acc[ACR][2], 0, 0, 0); \
    acc[ACR][3] = __builtin_amdgcn_mfma_f32_16x16x32_bf16( \
        av[IR][1], bv[3][1], acc[ACR][3], 0, 0, 0);

    // ---- prologue: stage tile 0, drain, publish ----
#pragma unroll
    for (int p = 0; p < 8; ++p)
        async_copy16(baseA + offg[p], &sA[offl[p]]);
#pragma unroll
    for (int p = 0; p < 4; ++p)
        async_copy16(baseB + offg[p], &sB[offl[p]]);
    asm volatile("s_waitcnt vmcnt(0)");
    __builtin_amdgcn_s_barrier();

#pragma unroll 1
    for (int t = 0; t < 64; ++t) {
        // ---- batch 1: B(8) + A rows 0..3 (8 reads) ----
        DSR(bv[0][0], bB0, 0);     DSR(bv[0][1], bB1, 0);
        DSR(bv[1][0], bB0, 2048);  DSR(bv[1][1], bB1, 2048);
        DSR(bv[2][0], bB0, 4096);  DSR(bv[2][1], bB1, 4096);
        DSR(bv[3][0], bB0, 6144);  DSR(bv[3][1], bB1, 6144);
        DSR(av[0][0], aB0, 0);     DSR(av[0][1], aB1, 0);
        DSR(av[1][0], aB0, 2048);  DSR(av[1][1], aB1, 2048);
        DSR(av[2][0], aB0, 4096);  DSR(av[2][1], aB1, 4096);
        DSR(av[3][0], aB0, 6144);  DSR(av[3][1], aB1, 6144);
        __builtin_amdgcn_s_setprio(1);
        WAITG(6); MROW(0, 0);
        WAITG(4); MROW(1, 1);
        WAITG(2); MROW(2, 2);
        WAITG(0); MROW(3, 3);
        __builtin_amdgcn_s_setprio(0);

        // ---- batch 2: A rows 4..7 (registers reused; WAR safe in-order) ----
        DSR(av[0][0], aB0, 8192);   DSR(av[0][1], aB1, 8192);
        DSR(av[1][0], aB0, 10240);  DSR(av[1][1], aB1, 10240);
        DSR(av[2][0], aB0, 12288);  DSR(av[2][1], aB1, 12288);
        DSR(av[3][0], aB0, 14336);  DSR(av[3][1], aB1, 14336);
        __builtin_amdgcn_s_setprio(1);
        WAITG(6); MROW(0, 4);
        WAITG(4); MROW(1, 5);
        WAITG(2); MROW(2, 6);
        WAITG(0); MROW(3, 7);
        __builtin_amdgcn_s_setprio(0);

        // ---- all reads of tile t complete; restage buffer ----
        __builtin_amdgcn_s_barrier();
        if (t < 63) {
            const int ko1 = (t + 1) << 6;
#pragma unroll
            for (int p = 0; p < 8; ++p)
                async_copy16(baseA + offg[p] + ko1, &sA[offl[p]]);
#pragma unroll
            for (int p = 0; p < 4; ++p)
                async_copy16(baseB + offg[p] + ko1, &sB[offl[p]]);
        }
        asm volatile("s_waitcnt vmcnt(0)");
        __builtin_amdgcn_s_barrier();
    }

#undef DSR
#undef WAITG
#undef MROW

    // ---- epilogue: C[row][col] = acc + bias[col]
#pragma unroll
    for (int i = 0; i < 8; ++i) {
        const int mrow = mb + wr * 128 + i * 16 + quad * 4;
#pragma unroll
        for (int j = 0; j < 4; ++j) {
            const int col = nb + wc * 64 + j * 16 + ln;
            float* cp = C + (size_t)mrow * OUT_F + col;
#pragma unroll
            for (int r = 0; r < 4; ++r)
                cp[(size_t)r * OUT_F] = acc[i][j][r] + bj[j];
        }
    }
}

extern "C" void kernel_launch(void* const* d_in, const int* in_sizes, int n_in,
                              void* d_out, int out_size, void* d_ws, size_t ws_size,
                              hipStream_t stream) {
    const float* x = (const float*)d_in[0];       // [2,2048,4096] fp32
    const int* wq = (const int*)d_in[1];          // [NUM_GROUPS*12]
    const float* wn = (const float*)d_in[2];      // [NUM_GROUPS]
    const float* bias = (const float*)d_in[3];    // [4096]
    float* out = (float*)d_out;                   // [2,2048,4096] fp32

    u16* Wb = (u16*)d_ws;                         // 32 MB
    u16* Xb = Wb + (size_t)OUT_F * IN_F;          // 32 MB

    prep_kernel<<<16384, 256, 0, stream>>>(x, wq, wn, Wb, Xb);
    gemm_bt_kernel<<<512, 256, 0, stream>>>(Xb, Wb, bias, out);
}